// Round 8
// baseline (19350.653 us; speedup 1.0000x reference)
//
#include <hip/hip_runtime.h>
#include <hip/hip_bf16.h>

#define N        2048
#define T_STEPS  8192
#define DIN      64
#define KW       128     // workgroups, 1 per CU
#define ROWS     16      // N / KW rows per WG
#define NTHR     256
#define CAP      320     // padded nonzeros per row (mean 205, sigma 13.6)
#define NNZL     20      // CAP / 16 nonzeros per lane (16-lane row groups)
#define NATOM    1024    // N/2 packed atoms per buffer
#define SCOPE_AG __HIP_MEMORY_SCOPE_AGENT

typedef unsigned long long u64;
typedef unsigned int v4u __attribute__((ext_vector_type(4)));

__device__ __forceinline__ unsigned bf16_bits(float x) {
    __hip_bfloat16 h = __float2bfloat16(x);
    return (unsigned)*(unsigned short*)&h;
}

// ---------------------------------------------------------------------------
// Packed exchange protocol: atom k of ex[t&1] covers state elems {2k, 2k+1}:
//   low 32 = tag t, high 32 = (bf16(s[2k+1])<<16 | bf16(s[2k])).
// Producer: one relaxed agent-scope 8-B store per row-pair (value+tag atom).
// Consumer: 16-B sc1 polls (each 8-B half self-validates; tearing harmless).
// Depth-2 flow control: a slot only advances to tag t+2 after ALL WGs
// consumed tag t (race-free). Leak path stays fp32 in registers — only the
// matvec input is bf16-quantized.
// ---------------------------------------------------------------------------

__global__ void init_kernel(u64* ex0) {
    int i = threadIdx.x + blockIdx.x * blockDim.x;
    if (i < NATOM) ex0[i] = 0ull;  // s_0 = 0 tagged 0; ex[1] keeps poison
                                   // tags (0xAAAAAAAA matches no t in range).
}

extern "C" __global__ void __launch_bounds__(NTHR, 1)
reservoir_scan(const float* __restrict__ W,
               const float* __restrict__ W_in,
               const float* __restrict__ u,
               const float* __restrict__ noise,
               u64* __restrict__ ex,                 // [2][NATOM] packed atoms
               __hip_bfloat16* __restrict__ states)  // [T][N]
{
    __shared__ u64   Wp[ROWS][CAP];   // 40 KB — sparse staging (init only)
    __shared__ float s_s[2][N];       // 16 KB — double-buffered state
    __shared__ int   s_timeout;

    const int tid = threadIdx.x;
    const int wg  = blockIdx.x;
    const int wv  = tid >> 6;        // wave 0..3
    const int ln  = tid & 63;        // lane 0..63
    const int r0  = wg * ROWS;       // first global row of this WG
    const int l   = ln & 15;         // lane-in-group
    const int g   = ln >> 4;         // row group 0..3
    const int lr  = wv * 4 + g;      // local row this group owns
    const int grow = r0 + lr;        // its global row

    // --- one-time sparse extraction: ballot-compact this wave's 4 rows ---
    for (int r = 0; r < 4; ++r) {
        const int xlr = wv * 4 + r;
        const size_t rowoff = (size_t)(r0 + xlr) * N;
        int base = 0;
        for (int ch = 0; ch < 32; ++ch) {
            int col = ch * 64 + ln;
            float w = W[rowoff + col];
            u64 m = __ballot(w != 0.0f);
            if (w != 0.0f) {
                int pos = base + (int)__popcll(m & ((1ull << ln) - 1ull));
                if (pos < CAP)
                    Wp[xlr][pos] = ((u64)__float_as_uint(w) << 32) | (unsigned)col;
            }
            base += (int)__popcll(m);
        }
        for (int p = base + ln; p < CAP; p += 64)
            Wp[xlr][p] = 0ull;        // val=0, col=0 — contributes nothing
    }
    if (tid == 0) s_timeout = 0;
    __syncthreads();

    // --- sparse slice to registers: lane (g,l) takes row lr's slots l+16i ---
    u64 wreg[NNZL];
    #pragma unroll
    for (int i = 0; i < NNZL; ++i)
        wreg[i] = Wp[lr][l + 16 * i];

    // --- input-drive weights: win[j] = W_in[grow][l + 16j] ---
    float win[4];
    #pragma unroll
    for (int j = 0; j < 4; ++j)
        win[j] = W_in[(size_t)grow * DIN + l + 16 * j];
    __syncthreads();   // Wp dead from here

    float sprev = 0.0f;          // this group's row state, fp32 (leak path)
    bool  use_b128 = true;

    for (int t = 0; t < T_STEPS; ++t) {
        const int buf = t & 1;

        // independent loads issued early — overlap with the spin-gather
        float ul = u[t * DIN + ln];
        float nz = noise[(size_t)t * N + grow];   // same addr per group

        u64* exb = ex + (size_t)buf * NATOM;
        bool got = false;

        if (use_b128) {
            const u64* a0 = exb + 2 * tid;          // atoms 2tid, 2tid+1
            const u64* a1 = exb + 2 * tid + 512;    // atoms 2tid+512, +513
            v4u q0, q1;
            int gd = 0;
            for (;;) {
                asm volatile("global_load_dwordx4 %0, %1, off sc1" : "=v"(q0) : "v"(a0));
                asm volatile("global_load_dwordx4 %0, %1, off sc1" : "=v"(q1) : "v"(a1));
                asm volatile("s_waitcnt vmcnt(0)" ::: "memory");
                int ok = (q0.x == (unsigned)t) + (q0.z == (unsigned)t)
                       + (q1.x == (unsigned)t) + (q1.z == (unsigned)t);
                if (__all(ok == 4)) { got = true; break; }
                if (++gd > 4096) { use_b128 = false; break; }  // sc1 hedge
            }
            if (got) {
                // unpack: elem 2k from low 16 (<<16 = fp32 bits), 2k+1 high 16
                float4 w0, w1;
                w0.x = __uint_as_float(q0.y << 16);
                w0.y = __uint_as_float(q0.y & 0xFFFF0000u);
                w0.z = __uint_as_float(q0.w << 16);
                w0.w = __uint_as_float(q0.w & 0xFFFF0000u);
                w1.x = __uint_as_float(q1.y << 16);
                w1.y = __uint_as_float(q1.y & 0xFFFF0000u);
                w1.z = __uint_as_float(q1.w << 16);
                w1.w = __uint_as_float(q1.w & 0xFFFF0000u);
                *(float4*)&s_s[buf][4 * tid]        = w0;
                *(float4*)&s_s[buf][4 * tid + 1024] = w1;
            }
        }
        if (!got) {
            // proven per-atom fallback (permanent if sc1 ever misbehaves)
            unsigned pend = 0xFu;
            int guard = 0;
            while (pend) {
                #pragma unroll
                for (int h = 0; h < 4; ++h) {
                    if (pend & (1u << h)) {
                        int atom = 2 * tid + (h & 1) + (h >> 1) * 512;
                        u64 v = __hip_atomic_load(&exb[atom], __ATOMIC_RELAXED, SCOPE_AG);
                        if ((unsigned)v == (unsigned)t) {
                            unsigned vals = (unsigned)(v >> 32);
                            s_s[buf][2 * atom]     = __uint_as_float(vals << 16);
                            s_s[buf][2 * atom + 1] = __uint_as_float(vals & 0xFFFF0000u);
                            pend &= ~(1u << h);
                        }
                    }
                }
                if (++guard > (1 << 17)) { s_timeout = 1; break; }
            }
        }

        __syncthreads();          // single barrier per step (s_s is dbuf'd)
        if (s_timeout) return;    // uniform abort instead of an eternal hang

        // --- sparse matvec: 20 LDS gathers + 20 FMAs per lane ---
        float acc = 0.0f;
        #pragma unroll
        for (int i = 0; i < NNZL; ++i) {
            unsigned col = (unsigned)wreg[i];
            float    w   = __uint_as_float((unsigned)(wreg[i] >> 32));
            acc += w * s_s[buf][col];
        }
        // input drive: Sum_j W_in[grow][l+16j] * u[t][l+16j] via shuffles
        #pragma unroll
        for (int j = 0; j < 4; ++j)
            acc += win[j] * __shfl(ul, l + 16 * j, 64);
        // reduce within the 16-lane group (all lanes end with the sum)
        #pragma unroll
        for (int off = 1; off < 16; off <<= 1)
            acc += __shfl_xor(acc, off, 64);

        // all 16 lanes of the group compute identical snew (fp32 leak path)
        float pre = acc + 0.01f * nz;
        float ax = __builtin_fabsf(pre);
        float e  = __builtin_amdgcn_exp2f(ax * 2.8853900817779268f);
        float th = 1.0f - 2.0f * __builtin_amdgcn_rcpf(e + 1.0f);
        th = __builtin_copysignf(th, pre);
        float snew = 0.7f * sprev + 0.3f * th;
        sprev = snew;

        // partner (odd row) value sits 16 lanes up in the same wave
        float    partner = __shfl(snew, (ln + 16) & 63, 64);
        unsigned us   = bf16_bits(snew);
        unsigned up   = bf16_bits(partner);
        unsigned vals = (up << 16) | us;

        if ((ln & 31) == 0) {     // lanes 0, 32: one atom per row-pair
            int atom = grow >> 1; // rows (grow, grow+1)
            u64 pk = ((u64)vals << 32) | (unsigned)(t + 1);
            __hip_atomic_store(&ex[(size_t)(buf ^ 1) * NATOM + atom], pk,
                               __ATOMIC_RELAXED, SCOPE_AG);
            // packed 4-B states write for both rows
            *(unsigned*)&states[(size_t)t * N + grow] = vals;
        }
        // no trailing barrier: overwriting s_s[buf] at step t+2 requires all
        // WGs' t+1 tags, which data-depend on their reads of s_s[buf].
    }
}

// ---------------------------------------------------------------------------
// readout: out[t][d] = states[t] . w_out[d] + b_out[d].
// ---------------------------------------------------------------------------
__global__ void __launch_bounds__(256)
out_gemm(const __hip_bfloat16* __restrict__ states,
         const float* __restrict__ w_out,
         const float* __restrict__ b_out,
         float* __restrict__ out)
{
    __shared__ float s_lds[4][N];   // 32 KiB
    const int tid = threadIdx.x;
    const int wv  = tid >> 6, ln = tid & 63;
    const int t0  = blockIdx.x * 4;

    for (int idx = tid; idx < 4 * N; idx += 256) {
        int tt = idx >> 11, kk = idx & (N - 1);
        s_lds[tt][kk] = __bfloat162float(states[(size_t)(t0 + tt) * N + kk]);
    }
    __syncthreads();

    const int t = t0 + wv;
    const float4* s4 = (const float4*)&s_lds[wv][0];
    for (int d = 0; d < 64; ++d) {
        const float4* w4 = (const float4*)(w_out + (size_t)d * N);
        float a = 0.0f;
        #pragma unroll
        for (int j = 0; j < 8; ++j) {
            const int ci = ln + 64 * j;
            float4 wv4 = w4[ci];
            float4 sv  = s4[ci];
            a += wv4.x * sv.x + wv4.y * sv.y + wv4.z * sv.z + wv4.w * sv.w;
        }
        #pragma unroll
        for (int off = 1; off < 64; off <<= 1) a += __shfl_xor(a, off, 64);
        if (ln == 0) out[t * 64 + d] = a + b_out[d];
    }
}

// ---------------------------------------------------------------------------
extern "C" void kernel_launch(void* const* d_in, const int* in_sizes, int n_in,
                              void* d_out, int out_size, void* d_ws, size_t ws_size,
                              hipStream_t stream)
{
    const float* u     = (const float*)d_in[0];   // (T, DIN)
    const float* noise = (const float*)d_in[1];   // (T, N)
    const float* W_in  = (const float*)d_in[2];   // (N, DIN)
    const float* W     = (const float*)d_in[3];   // (N, N)
    const float* w_out = (const float*)d_in[4];   // (64, N)
    const float* b_out = (const float*)d_in[5];   // (64,)
    float* out = (float*)d_out;

    // workspace: [0, 16K): ex[2][NATOM] u64 | [64K, 64K+32M): states bf16
    u64* ex                = (u64*)d_ws;
    __hip_bfloat16* states = (__hip_bfloat16*)((char*)d_ws + 65536);

    hipLaunchKernelGGL(init_kernel, dim3((NATOM + 255) / 256), dim3(256), 0,
                       stream, ex);

    void* args[] = { (void*)&W, (void*)&W_in, (void*)&u, (void*)&noise,
                     (void*)&ex, (void*)&states };
    hipLaunchCooperativeKernel((const void*)reservoir_scan,
                               dim3(KW), dim3(NTHR), args, 0, stream);

    hipLaunchKernelGGL(out_gemm, dim3(T_STEPS / 4), dim3(256), 0, stream,
                       states, w_out, b_out, out);
}

// Round 9
// 13336.617 us; speedup vs baseline: 1.4509x; 1.4509x over previous
//
#include <hip/hip_runtime.h>
#include <hip/hip_bf16.h>

#define N        2048
#define T_STEPS  8192
#define DIN      64
#define KW       128     // workgroups, 1 per CU
#define ROWS     16      // N / KW rows per WG
#define NTHR     256
#define CAP      320     // padded nonzeros per row (mean 205, sigma 13.6)
#define NNZL     20      // CAP / 16 nonzeros per lane (16-lane row groups)
#define SCOPE_AG __HIP_MEMORY_SCOPE_AGENT

typedef unsigned long long u64;
typedef unsigned int v4u __attribute__((ext_vector_type(4)));

// ---------------------------------------------------------------------------
// Exchange protocol (R6 layout — proven fastest): ex[t&1][k] holds s_t[k] as
// (fp32_bits<<32)|t. Producers: one relaxed agent-scope 8-B store per row.
// Consumers: 16-B sc1 polls with MONOTONIC SLOT RETIREMENT — a slot that
// validates is stashed to LDS immediately and never re-polled (tags only
// advance t-2 -> t within a wait, so retirement is race-free). Depth-2 flow
// control: a slot only advances to tag t+2 after ALL WGs consumed tag t.
// ---------------------------------------------------------------------------

__global__ void init_kernel(u64* ex0) {
    int i = threadIdx.x + blockIdx.x * blockDim.x;
    if (i < N) ex0[i] = 0ull;   // s_0 = 0.0f tagged 0; ex[1] keeps poison
                                // tags (0xAAAAAAAA matches no t in range).
}

extern "C" __global__ void __launch_bounds__(NTHR, 1)
reservoir_scan(const float* __restrict__ W,
               const float* __restrict__ W_in,
               const float* __restrict__ u,
               const float* __restrict__ noise,
               u64* __restrict__ ex,                 // [2][N] value+tag atoms
               __hip_bfloat16* __restrict__ states)  // [T][N]
{
    __shared__ u64   Wp[ROWS][CAP];   // 40 KB — sparse staging (init only)
    __shared__ float s_s[2][N];       // 16 KB — double-buffered state
    __shared__ int   s_timeout;

    const int tid = threadIdx.x;
    const int wg  = blockIdx.x;
    const int wv  = tid >> 6;        // wave 0..3
    const int ln  = tid & 63;        // lane 0..63
    const int r0  = wg * ROWS;       // first global row of this WG
    const int l   = ln & 15;         // lane-in-group
    const int g   = ln >> 4;         // row group 0..3
    const int lr  = wv * 4 + g;      // local row this group owns
    const int grow = r0 + lr;        // its global row

    // --- one-time sparse extraction: ballot-compact this wave's 4 rows ---
    for (int r = 0; r < 4; ++r) {
        const int xlr = wv * 4 + r;
        const size_t rowoff = (size_t)(r0 + xlr) * N;
        int base = 0;
        for (int ch = 0; ch < 32; ++ch) {
            int col = ch * 64 + ln;
            float w = W[rowoff + col];
            u64 m = __ballot(w != 0.0f);
            if (w != 0.0f) {
                int pos = base + (int)__popcll(m & ((1ull << ln) - 1ull));
                if (pos < CAP)
                    Wp[xlr][pos] = ((u64)__float_as_uint(w) << 32) | (unsigned)col;
            }
            base += (int)__popcll(m);
        }
        for (int p = base + ln; p < CAP; p += 64)
            Wp[xlr][p] = 0ull;        // val=0, col=0 — contributes nothing
    }
    if (tid == 0) s_timeout = 0;
    __syncthreads();

    // --- sparse slice to registers: lane (g,l) takes row lr's slots l+16i ---
    u64 wreg[NNZL];
    #pragma unroll
    for (int i = 0; i < NNZL; ++i)
        wreg[i] = Wp[lr][l + 16 * i];

    // --- input-drive weights: win[j] = W_in[grow][l + 16j] ---
    float win[4];
    #pragma unroll
    for (int j = 0; j < 4; ++j)
        win[j] = W_in[(size_t)grow * DIN + l + 16 * j];
    __syncthreads();   // Wp dead from here

    // this thread's 4 atom-pair slots: pair base p0 + 64s, s = 0..3
    const int p0 = wv * 256 + ln;
    bool use_b128 = true;

    for (int t = 0; t < T_STEPS; ++t) {
        const int buf = t & 1;

        // independent loads issued early — overlap with the spin-gather
        float ul = u[t * DIN + ln];
        float nz = 0.0f;
        if (l == 0) nz = noise[(size_t)t * N + grow];

        u64* exb = ex + (size_t)buf * N;

        if (use_b128) {
            const u64* A0 = exb + 2 * (p0);
            const u64* A1 = exb + 2 * (p0 + 64);
            const u64* A2 = exb + 2 * (p0 + 128);
            const u64* A3 = exb + 2 * (p0 + 192);
            v4u q0, q1, q2, q3;
            unsigned live = 0xFu;     // wave-uniform pending-slot mask
            int gd = 0;
            while (live) {
                if (live & 1u) asm volatile("global_load_dwordx4 %0, %1, off sc1" : "=v"(q0) : "v"(A0));
                if (live & 2u) asm volatile("global_load_dwordx4 %0, %1, off sc1" : "=v"(q1) : "v"(A1));
                if (live & 4u) asm volatile("global_load_dwordx4 %0, %1, off sc1" : "=v"(q2) : "v"(A2));
                if (live & 8u) asm volatile("global_load_dwordx4 %0, %1, off sc1" : "=v"(q3) : "v"(A3));
                asm volatile("s_waitcnt vmcnt(0)" ::: "memory");
                // retire any slot whose both tags match across the wave
                if ((live & 1u) && __all((q0.x == (unsigned)t) && (q0.z == (unsigned)t))) {
                    *(float2*)&s_s[buf][2 * (p0      )] = make_float2(__uint_as_float(q0.y), __uint_as_float(q0.w));
                    live &= ~1u;
                }
                if ((live & 2u) && __all((q1.x == (unsigned)t) && (q1.z == (unsigned)t))) {
                    *(float2*)&s_s[buf][2 * (p0 +  64)] = make_float2(__uint_as_float(q1.y), __uint_as_float(q1.w));
                    live &= ~2u;
                }
                if ((live & 4u) && __all((q2.x == (unsigned)t) && (q2.z == (unsigned)t))) {
                    *(float2*)&s_s[buf][2 * (p0 + 128)] = make_float2(__uint_as_float(q2.y), __uint_as_float(q2.w));
                    live &= ~4u;
                }
                if ((live & 8u) && __all((q3.x == (unsigned)t) && (q3.z == (unsigned)t))) {
                    *(float2*)&s_s[buf][2 * (p0 + 192)] = make_float2(__uint_as_float(q3.y), __uint_as_float(q3.w));
                    live &= ~8u;
                }
                if (++gd > (1 << 16)) { use_b128 = false; break; }  // hedge
            }
        }
        if (!use_b128) {
            // per-atom monotonic fallback (idempotent re-stash is harmless)
            unsigned pend = 0xFFu;
            int guard = 0;
            while (pend) {
                #pragma unroll
                for (int h = 0; h < 8; ++h) {
                    if (pend & (1u << h)) {
                        int atom = 2 * (p0 + 64 * (h >> 1)) + (h & 1);
                        u64 v = __hip_atomic_load(&exb[atom], __ATOMIC_RELAXED, SCOPE_AG);
                        if ((unsigned)v == (unsigned)t) {
                            s_s[buf][atom] = __uint_as_float((unsigned)(v >> 32));
                            pend &= ~(1u << h);
                        }
                    }
                }
                if (++guard > (1 << 17)) { s_timeout = 1; break; }
            }
        }

        __syncthreads();          // single barrier per step (s_s is dbuf'd)
        if (s_timeout) return;    // uniform abort instead of an eternal hang

        // --- sparse matvec: 20 LDS gathers + 20 FMAs per lane ---
        float acc = 0.0f;
        #pragma unroll
        for (int i = 0; i < NNZL; ++i) {
            unsigned col = (unsigned)wreg[i];
            float    w   = __uint_as_float((unsigned)(wreg[i] >> 32));
            acc += w * s_s[buf][col];
        }
        // input drive: Sum_j W_in[grow][l+16j] * u[t][l+16j] via shuffles
        #pragma unroll
        for (int j = 0; j < 4; ++j)
            acc += win[j] * __shfl(ul, l + 16 * j, 64);
        // reduce within the 16-lane group (all 4 rows of the wave at once)
        #pragma unroll
        for (int off = 1; off < 16; off <<= 1)
            acc += __shfl_xor(acc, off, 64);

        if (l == 0) {
            float pre = acc + 0.01f * nz;
            // fast tanh: sign * (1 - 2/(exp2(2*log2e*|x|)+1))
            float ax = __builtin_fabsf(pre);
            float e  = __builtin_amdgcn_exp2f(ax * 2.8853900817779268f);
            float th = 1.0f - 2.0f * __builtin_amdgcn_rcpf(e + 1.0f);
            th = __builtin_copysignf(th, pre);
            float snew = 0.7f * s_s[buf][grow] + 0.3f * th;
            u64 pk = ((u64)__float_as_uint(snew) << 32) | (unsigned)(t + 1);
            __hip_atomic_store(&ex[(size_t)(buf ^ 1) * N + grow], pk,
                               __ATOMIC_RELAXED, SCOPE_AG);
            states[(size_t)t * N + grow] = __float2bfloat16(snew);
        }
        // no trailing barrier: overwriting s_s[buf] at step t+2 requires all
        // WGs' t+1 tags, which data-depend on their reads of s_s[buf].
    }
}

// ---------------------------------------------------------------------------
// readout: out[t][d] = states[t] . w_out[d] + b_out[d].
// ---------------------------------------------------------------------------
__global__ void __launch_bounds__(256)
out_gemm(const __hip_bfloat16* __restrict__ states,
         const float* __restrict__ w_out,
         const float* __restrict__ b_out,
         float* __restrict__ out)
{
    __shared__ float s_lds[4][N];   // 32 KiB
    const int tid = threadIdx.x;
    const int wv  = tid >> 6, ln = tid & 63;
    const int t0  = blockIdx.x * 4;

    for (int idx = tid; idx < 4 * N; idx += 256) {
        int tt = idx >> 11, kk = idx & (N - 1);
        s_lds[tt][kk] = __bfloat162float(states[(size_t)(t0 + tt) * N + kk]);
    }
    __syncthreads();

    const int t = t0 + wv;
    const float4* s4 = (const float4*)&s_lds[wv][0];
    for (int d = 0; d < 64; ++d) {
        const float4* w4 = (const float4*)(w_out + (size_t)d * N);
        float a = 0.0f;
        #pragma unroll
        for (int j = 0; j < 8; ++j) {
            const int ci = ln + 64 * j;
            float4 wv4 = w4[ci];
            float4 sv  = s4[ci];
            a += wv4.x * sv.x + wv4.y * sv.y + wv4.z * sv.z + wv4.w * sv.w;
        }
        #pragma unroll
        for (int off = 1; off < 64; off <<= 1) a += __shfl_xor(a, off, 64);
        if (ln == 0) out[t * 64 + d] = a + b_out[d];
    }
}

// ---------------------------------------------------------------------------
extern "C" void kernel_launch(void* const* d_in, const int* in_sizes, int n_in,
                              void* d_out, int out_size, void* d_ws, size_t ws_size,
                              hipStream_t stream)
{
    const float* u     = (const float*)d_in[0];   // (T, DIN)
    const float* noise = (const float*)d_in[1];   // (T, N)
    const float* W_in  = (const float*)d_in[2];   // (N, DIN)
    const float* W     = (const float*)d_in[3];   // (N, N)
    const float* w_out = (const float*)d_in[4];   // (64, N)
    const float* b_out = (const float*)d_in[5];   // (64,)
    float* out = (float*)d_out;

    // workspace: [0, 32K): ex[2][N] u64 | [64K, 64K+32M): states bf16
    u64* ex                = (u64*)d_ws;
    __hip_bfloat16* states = (__hip_bfloat16*)((char*)d_ws + 65536);

    hipLaunchKernelGGL(init_kernel, dim3((N + 255) / 256), dim3(256), 0, stream,
                       ex);

    void* args[] = { (void*)&W, (void*)&W_in, (void*)&u, (void*)&noise,
                     (void*)&ex, (void*)&states };
    hipLaunchCooperativeKernel((const void*)reservoir_scan,
                               dim3(KW), dim3(NTHR), args, 0, stream);

    hipLaunchKernelGGL(out_gemm, dim3(T_STEPS / 4), dim3(256), 0, stream,
                       states, w_out, b_out, out);
}